// Round 10
// baseline (114.648 us; speedup 1.0000x reference)
//
#include <hip/hip_runtime.h>
#include <hip/hip_bf16.h>
#include <math.h>

// PolicyHead, fused, all-LDS-staged, counted-vmcnt, BM=64 (period-halving):
//   kLN = LayerNorm(key_table); bqk = kLN.bq
//   Wk  = Wq @ kLN^T (4096x128-pad f16) FRAGMENT-TILED (Bf)
//   out[b] = log_softmax(mask(gather(backbone[b]@Wk + bqk)/16) + bias)
//
// R9 post-mortem: depth-3 == depth-2 (~3600cyc/period) -> period is NOT
// latency-limited; hypothesis: fixed per-period cost (2 barriers x 8 waves +
// waitcnt + issue) ~1.2k cyc dominates at 128 periods/CU. R10: BM=64 ->
// 64 periods/CU at same total bytes (A 268MB; B halves to 256MB, L2-res).
// Depth-2 ring, 64KB LDS, vmcnt(4) in-loop (4 gl_lds/wave/stage), raw
// s_barrier, no vmcnt(0) until tail. Grid 256 = 1 block/CU.
//
// ws: [0,1MB) Bf f16 | [1MB,+83K) tableLN | [1MB+128K,+512B) bqk

typedef _Float16 half8_t __attribute__((ext_vector_type(8)));
typedef float    f32x4_t __attribute__((ext_vector_type(4)));

#define NUM_B 16384
#define D_IN  4096
#define D_Q   256
#define N_ACT 40

__device__ __forceinline__ half8_t cvt8(const float4 a, const float4 b) {
  half8_t h;
  h[0] = (_Float16)a.x; h[1] = (_Float16)a.y; h[2] = (_Float16)a.z; h[3] = (_Float16)a.w;
  h[4] = (_Float16)b.x; h[5] = (_Float16)b.y; h[6] = (_Float16)b.z; h[7] = (_Float16)b.w;
  return h;
}
__device__ __forceinline__ void gl_lds16f(const float* g, float* l) {
  __builtin_amdgcn_global_load_lds(
      (const __attribute__((address_space(1))) void*)g,
      (__attribute__((address_space(3))) void*)l, 16, 0, 0);
}
__device__ __forceinline__ void gl_lds16h(const _Float16* g, _Float16* l) {
  __builtin_amdgcn_global_load_lds(
      (const __attribute__((address_space(1))) void*)g,
      (__attribute__((address_space(3))) void*)l, 16, 0, 0);
}

// ---------------------------------------------------------------------------
__global__ __launch_bounds__(256) void ln_table_k(const float* __restrict__ kt,
                                                  const float* __restrict__ gamma,
                                                  const float* __restrict__ beta,
                                                  const float* __restrict__ bq,
                                                  float* __restrict__ out,
                                                  float* __restrict__ bqk) {
  __shared__ float red[8];
  __shared__ float red2[4];
  const int t = threadIdx.x, r = blockIdx.x;
  float v = kt[r * 256 + t];
  float s = v, sq = v * v;
#pragma unroll
  for (int off = 1; off < 64; off <<= 1) {
    s  += __shfl_xor(s, off);
    sq += __shfl_xor(sq, off);
  }
  if ((t & 63) == 0) { red[t >> 6] = s; red[4 + (t >> 6)] = sq; }
  __syncthreads();
  s  = red[0] + red[1] + red[2] + red[3];
  sq = red[4] + red[5] + red[6] + red[7];
  const float mu  = s * (1.0f / 256.0f);
  const float var = sq * (1.0f / 256.0f) - mu * mu;
  const float inv = 1.0f / sqrtf(var + 1e-5f);
  const float o = (v - mu) * inv * gamma[t] + beta[t];
  out[r * 256 + t] = o;
  float p = o * bq[t];
#pragma unroll
  for (int off = 1; off < 64; off <<= 1) p += __shfl_xor(p, off);
  if ((t & 63) == 0) red2[t >> 6] = p;
  __syncthreads();
  if (t == 0) bqk[r] = red2[0] + red2[1] + red2[2] + red2[3];
}

// ---------------------------------------------------------------------------
// Wk = Wq(4096x256) @ kLN^T(256x81->128 zero-pad), f16, fragment-tiled:
// element (k,n) -> halves idx ((k>>5)*8+(n>>4))*512 + (((k>>3)&3)*16+(n&15))*8 + (k&7)
__global__ __launch_bounds__(256) void wk_gemm_k(const float* __restrict__ Wq,
                                                 const float* __restrict__ tbl,
                                                 _Float16* __restrict__ Bf) {
  const int lane = threadIdx.x & 63, w = threadIdx.x >> 6;
  const int wm = w >> 1, wn = w & 1;
  const int m0 = blockIdx.x * 64 + wm * 32;
  const int n0 = wn * 64;
  const int fr = lane & 15, fg = lane >> 4;
  f32x4_t acc[2][4] = {};
  for (int k0 = 0; k0 < 256; k0 += 32) {
    half8_t af[2], bf[4];
#pragma unroll
    for (int i = 0; i < 2; ++i) {
      const float* p = Wq + (size_t)(m0 + i * 16 + fr) * D_Q + k0 + fg * 8;
      af[i] = cvt8(*(const float4*)p, *(const float4*)(p + 4));
    }
#pragma unroll
    for (int j = 0; j < 4; ++j) {
      const int n = n0 + j * 16 + fr;
      if (n < 81) {
        const float* p = tbl + (size_t)n * D_Q + k0 + fg * 8;
        bf[j] = cvt8(*(const float4*)p, *(const float4*)(p + 4));
      } else {
        bf[j] = (half8_t)(_Float16)0.0f;
      }
    }
#pragma unroll
    for (int i = 0; i < 2; ++i)
#pragma unroll
      for (int j = 0; j < 4; ++j)
        acc[i][j] = __builtin_amdgcn_mfma_f32_16x16x32_f16(af[i], bf[j], acc[i][j], 0, 0, 0);
  }
#pragma unroll
  for (int i = 0; i < 2; ++i)
#pragma unroll
    for (int j = 0; j < 4; ++j)
#pragma unroll
      for (int r = 0; r < 4; ++r) {
        const int k = m0 + i * 16 + fg * 4 + r;
        const int n = n0 + j * 16 + fr;
        const int kt32 = k >> 5, fgb = (k >> 3) & 3, e = k & 7;
        const int jg = n >> 4, frb = n & 15;
        Bf[(((size_t)kt32 * 8 + jg) * 64 + fgb * 16 + frb) * 8 + e] =
            (_Float16)acc[i][j][r];
      }
}

// ---------------------------------------------------------------------------
// Fused GEMM + gather + bias + log_softmax.
// Block: 512 thr / 8 waves, 64 batch rows x 128 cols, K=4096, BK=64 (64 it).
// LDS depth-2 ring: Af[2][4096] f32 (32KB, source-swizzled u^=(row&7)),
// Bl[2][8192] f16 (32KB, linear copy of Bf chunk). Total 64KB.
// Per wave per iter: exactly 4 global_load_lds (2 A + 2 B); in-loop wait
// s_waitcnt vmcnt(4) (next stage in flight), vmcnt(0) only at tail.
// Wave tile 32x32: wm=w>>2 (row half), wn=w&3 (col quarter).
__global__ __launch_bounds__(512) void gemm_fused_k(const float* __restrict__ A,
                                                    const _Float16* __restrict__ Bf,
                                                    const float* __restrict__ bqk,
                                                    const int* __restrict__ va,
                                                    const int* __restrict__ phase,
                                                    const int* __restrict__ trick,
                                                    const float* __restrict__ psig,
                                                    float* __restrict__ out) {
  __shared__ __align__(16) char smem[65536];    // 32KB A + 32KB B
  float*    Afs = (float*)smem;                 // [2][4096] f32
  _Float16* Bls = (_Float16*)(smem + 32768);    // [2][8192] f16

  const int t = threadIdx.x, lane = t & 63, w = t >> 6;
  const int fr = lane & 15, fg = lane >> 4;
  const size_t row0 = (size_t)blockIdx.x * 64;

  // ---- staging: 32 instrs, id = w*4+q (0..31). id<16: A rows id*4+(lane>>4),
  //      256B/row slice, source-XOR-swizzled; else: B linear 1KB chunks.
#define STAGE(T, P)                                                            \
  do {                                                                         \
    float* abase = Afs + (P)*4096;                                             \
    _Float16* bbase = Bls + (P)*8192;                                          \
    _Pragma("unroll") for (int q_ = 0; q_ < 4; ++q_) {                         \
      const int id_ = w * 4 + q_;                                              \
      if (id_ < 16) {                                                          \
        const int r_ = id_ * 4 + (lane >> 4);                                  \
        gl_lds16f(A + (size_t)(row0 + r_) * D_IN + (T)*64 +                    \
                      (((lane & 15) ^ (r_ & 7)) << 2),                         \
                  abase + id_ * 256);                                          \
      } else {                                                                 \
        const int ib_ = id_ - 16;                                              \
        gl_lds16h(Bf + (size_t)(T)*8192 + ib_ * 512 + lane * 8,                \
                  bbase + ib_ * 512);                                          \
      }                                                                        \
    }                                                                          \
  } while (0)

  // ---- frag read offsets
  const int wm = w >> 2, wn = w & 3;  // wave tile: rows wm*32..+32, cols wn*32..+32
  int aoff[2][2][2], boff[2][2];
#pragma unroll
  for (int i = 0; i < 2; ++i)
#pragma unroll
    for (int c = 0; c < 2; ++c)
#pragma unroll
      for (int h = 0; h < 2; ++h)
        aoff[i][c][h] = (wm * 32 + i * 16 + fr) * 64 +
                        (((c * 8 + fg * 2 + h) ^ (fr & 7)) * 4);
#pragma unroll
  for (int c = 0; c < 2; ++c)
#pragma unroll
    for (int j = 0; j < 2; ++j)
      boff[c][j] = c * 4096 + (wn * 2 + j) * 512 + lane * 8;

  f32x4_t acc[2][2] = {};

  STAGE(0, 0);
  for (int kt = 0; kt < 64; ++kt) {
    if (kt < 63) STAGE(kt + 1, (kt + 1) & 1);
    __builtin_amdgcn_sched_barrier(0);
    if (kt < 63) asm volatile("s_waitcnt vmcnt(4)" ::: "memory");
    else         asm volatile("s_waitcnt vmcnt(0)" ::: "memory");
    __builtin_amdgcn_s_barrier();
    __builtin_amdgcn_sched_barrier(0);

    const float*    Ap = Afs + (kt & 1) * 4096;
    const _Float16* Bp = Bls + (kt & 1) * 8192;
#pragma unroll
    for (int c = 0; c < 2; ++c) {
      half8_t bfv[2];
#pragma unroll
      for (int j = 0; j < 2; ++j) bfv[j] = *(const half8_t*)(Bp + boff[c][j]);
#pragma unroll
      for (int i = 0; i < 2; ++i) {
        const float4 x0 = *(const float4*)(Ap + aoff[i][c][0]);
        const float4 x1 = *(const float4*)(Ap + aoff[i][c][1]);
        const half8_t af = cvt8(x0, x1);
#pragma unroll
        for (int j = 0; j < 2; ++j)
          acc[i][j] = __builtin_amdgcn_mfma_f32_16x16x32_f16(af, bfv[j], acc[i][j], 0, 0, 0);
      }
    }
    asm volatile("s_waitcnt lgkmcnt(0)" ::: "memory");
    __builtin_amdgcn_s_barrier();
    __builtin_amdgcn_sched_barrier(0);
  }
#undef STAGE

  // ---- epilogue: C (64x132 f32 = 33.8KB) overlays dead staging LDS
  __syncthreads();
  float* C = (float*)smem;
#pragma unroll
  for (int i = 0; i < 2; ++i)
#pragma unroll
    for (int j = 0; j < 2; ++j) {
      const int col = wn * 32 + j * 16 + fr;
#pragma unroll
      for (int r = 0; r < 4; ++r)
        C[(wm * 32 + i * 16 + fg * 4 + r) * 132 + col] = acc[i][j][r];
    }
  __syncthreads();

  // gather + bias + log_softmax: 8 waves x 8 rows
  for (int rr = 0; rr < 8; ++rr) {
    const int row = w * 8 + rr;
    const size_t b = row0 + row;
    int rank = -1, suit = 0;
    if (lane < N_ACT) {
      rank = va[(b * N_ACT + lane) * 2];
      suit = va[(b * N_ACT + lane) * 2 + 1];
    }
    const int ph = phase[b];
    const bool valid = (rank >= 0);
    const int aidx = valid ? (suit == 4 ? 80 : ph * 40 + suit * 9 + rank) : -1;
    const int nvalid = __popcll(__ballot(valid));

    float logit = -INFINITY;
    if (valid) logit = (C[row * 132 + aidx] + bqk[aidx]) * 0.0625f;  // /sqrt(256)

    if (ph == 1 && lane == 0) {
      const float ps = psig[trick[b]];
      const float nv = (float)nvalid;
      const float wv = (nv == 1.0f) ? 0.0f
                                    : logf(fmaxf((1.0f - ps) / ps * (nv - 1.0f), 1e-5f));
      logit += wv;
    }

    float m = logit;
#pragma unroll
    for (int off = 1; off < 64; off <<= 1) m = fmaxf(m, __shfl_xor(m, off));
    const float e = expf(logit - m);
    float ssum = e;
#pragma unroll
    for (int off = 1; off < 64; off <<= 1) ssum += __shfl_xor(ssum, off);
    const float o = logit - m - logf(ssum);
    // finite sentinel at masked positions (ref has -inf; (-inf)-(-inf)=NaN)
    if (lane < N_ACT) out[b * N_ACT + lane] = valid ? o : -3.0e38f;
  }
}

// ---------------------------------------------------------------------------
extern "C" void kernel_launch(void* const* d_in, const int* in_sizes, int n_in,
                              void* d_out, int out_size, void* d_ws, size_t ws_size,
                              hipStream_t stream) {
  const float* backbone = (const float*)d_in[0];
  const int*   va       = (const int*)d_in[1];
  const int*   phase    = (const int*)d_in[2];
  const int*   trick    = (const int*)d_in[3];
  const float* Wq       = (const float*)d_in[4];
  const float* bq       = (const float*)d_in[5];
  const float* keytab   = (const float*)d_in[6];
  const float* gamma    = (const float*)d_in[7];
  const float* beta     = (const float*)d_in[8];
  const float* psig     = (const float*)d_in[9];
  float* out = (float*)d_out;

  char* ws = (char*)d_ws;
  _Float16* Bf   = (_Float16*)ws;                             // 1 MB
  float* tableLN = (float*)(ws + (1u << 20));                 // 83 KB
  float* bqk     = (float*)(ws + (1u << 20) + (128u << 10));  // 324 B

  ln_table_k<<<dim3(81), 256, 0, stream>>>(keytab, gamma, beta, bq, tableLN, bqk);
  wk_gemm_k<<<dim3(64), 256, 0, stream>>>(Wq, tableLN, Bf);
  gemm_fused_k<<<dim3(NUM_B / 64), 512, 0, stream>>>(backbone, Bf, bqk, va,
                                                     phase, trick, psig, out);
}

// Round 11
// 89.684 us; speedup vs baseline: 1.2784x; 1.2784x over previous
//
#include <hip/hip_runtime.h>
#include <hip/hip_bf16.h>
#include <math.h>

// PolicyHead, staged-byte-minimized formulation:
//   kLN = LayerNorm(key_table); bqk = kLN.bq
//   Wk  = Wq @ kLN^T (4096x128-pad f16) FRAGMENT-TILED (Bf)
//   part[ks] = A[:, ks*2048:+2048] @ Wk-slice  (split-K x2)
//   out = log_softmax(mask(gather(sum part + bqk)/16) + bias)
//
// Cross-round model: gl_lds staging throughput ~13 B/cyc/CU (R3/R4/R8/R10 all
// consistent). R8 staged 3.05MB/CU (A 1.05 f32 + B 2.0 f16) -> 94us floor.
// R11: BM=64 halves B re-staging (1MB/CU), split-K x2 keeps 512 blocks =
// 2 blocks/CU co-resident (R10's 1 block/CU exposed period bubbles).
// Total 2.05MB/CU @ ~13B/cyc ~= 66us. Depth-2 ring, vmcnt(4) in loop,
// raw s_barrier, vmcnt(0) only at tail.
//
// ws: [0,1MB) Bf f16 | [1MB,+83K) tableLN | [1MB+128K,+512B) bqk
//     [2MB,+16.8MB) part f32 [2][16384][128]

typedef _Float16 half8_t __attribute__((ext_vector_type(8)));
typedef float    f32x4_t __attribute__((ext_vector_type(4)));

#define NUM_B 16384
#define D_IN  4096
#define D_Q   256
#define N_ACT 40

__device__ __forceinline__ half8_t cvt8(const float4 a, const float4 b) {
  half8_t h;
  h[0] = (_Float16)a.x; h[1] = (_Float16)a.y; h[2] = (_Float16)a.z; h[3] = (_Float16)a.w;
  h[4] = (_Float16)b.x; h[5] = (_Float16)b.y; h[6] = (_Float16)b.z; h[7] = (_Float16)b.w;
  return h;
}
__device__ __forceinline__ void gl_lds16f(const float* g, float* l) {
  __builtin_amdgcn_global_load_lds(
      (const __attribute__((address_space(1))) void*)g,
      (__attribute__((address_space(3))) void*)l, 16, 0, 0);
}
__device__ __forceinline__ void gl_lds16h(const _Float16* g, _Float16* l) {
  __builtin_amdgcn_global_load_lds(
      (const __attribute__((address_space(1))) void*)g,
      (__attribute__((address_space(3))) void*)l, 16, 0, 0);
}

// ---------------------------------------------------------------------------
__global__ __launch_bounds__(256) void ln_table_k(const float* __restrict__ kt,
                                                  const float* __restrict__ gamma,
                                                  const float* __restrict__ beta,
                                                  const float* __restrict__ bq,
                                                  float* __restrict__ out,
                                                  float* __restrict__ bqk) {
  __shared__ float red[8];
  __shared__ float red2[4];
  const int t = threadIdx.x, r = blockIdx.x;
  float v = kt[r * 256 + t];
  float s = v, sq = v * v;
#pragma unroll
  for (int off = 1; off < 64; off <<= 1) {
    s  += __shfl_xor(s, off);
    sq += __shfl_xor(sq, off);
  }
  if ((t & 63) == 0) { red[t >> 6] = s; red[4 + (t >> 6)] = sq; }
  __syncthreads();
  s  = red[0] + red[1] + red[2] + red[3];
  sq = red[4] + red[5] + red[6] + red[7];
  const float mu  = s * (1.0f / 256.0f);
  const float var = sq * (1.0f / 256.0f) - mu * mu;
  const float inv = 1.0f / sqrtf(var + 1e-5f);
  const float o = (v - mu) * inv * gamma[t] + beta[t];
  out[r * 256 + t] = o;
  float p = o * bq[t];
#pragma unroll
  for (int off = 1; off < 64; off <<= 1) p += __shfl_xor(p, off);
  if ((t & 63) == 0) red2[t >> 6] = p;
  __syncthreads();
  if (t == 0) bqk[r] = red2[0] + red2[1] + red2[2] + red2[3];
}

// ---------------------------------------------------------------------------
// Wk = Wq(4096x256) @ kLN^T(256x81->128 zero-pad), f16, fragment-tiled:
// element (k,n) -> halves idx ((k>>5)*8+(n>>4))*512 + (((k>>3)&3)*16+(n&15))*8 + (k&7)
__global__ __launch_bounds__(256) void wk_gemm_k(const float* __restrict__ Wq,
                                                 const float* __restrict__ tbl,
                                                 _Float16* __restrict__ Bf) {
  const int lane = threadIdx.x & 63, w = threadIdx.x >> 6;
  const int wm = w >> 1, wn = w & 1;
  const int m0 = blockIdx.x * 64 + wm * 32;
  const int n0 = wn * 64;
  const int fr = lane & 15, fg = lane >> 4;
  f32x4_t acc[2][4] = {};
  for (int k0 = 0; k0 < 256; k0 += 32) {
    half8_t af[2], bf[4];
#pragma unroll
    for (int i = 0; i < 2; ++i) {
      const float* p = Wq + (size_t)(m0 + i * 16 + fr) * D_Q + k0 + fg * 8;
      af[i] = cvt8(*(const float4*)p, *(const float4*)(p + 4));
    }
#pragma unroll
    for (int j = 0; j < 4; ++j) {
      const int n = n0 + j * 16 + fr;
      if (n < 81) {
        const float* p = tbl + (size_t)n * D_Q + k0 + fg * 8;
        bf[j] = cvt8(*(const float4*)p, *(const float4*)(p + 4));
      } else {
        bf[j] = (half8_t)(_Float16)0.0f;
      }
    }
#pragma unroll
    for (int i = 0; i < 2; ++i)
#pragma unroll
      for (int j = 0; j < 4; ++j)
        acc[i][j] = __builtin_amdgcn_mfma_f32_16x16x32_f16(af[i], bf[j], acc[i][j], 0, 0, 0);
  }
#pragma unroll
  for (int i = 0; i < 2; ++i)
#pragma unroll
    for (int j = 0; j < 4; ++j)
#pragma unroll
      for (int r = 0; r < 4; ++r) {
        const int k = m0 + i * 16 + fg * 4 + r;
        const int n = n0 + j * 16 + fr;
        const int kt32 = k >> 5, fgb = (k >> 3) & 3, e = k & 7;
        const int jg = n >> 4, frb = n & 15;
        Bf[(((size_t)kt32 * 8 + jg) * 64 + fgb * 16 + frb) * 8 + e] =
            (_Float16)acc[i][j][r];
      }
}

// ---------------------------------------------------------------------------
// GEMM partials: block (bx, ks) owns 64 batch rows x 128 cols x K-slice
// ks*2048..+2048 (32 iters of BK=64). 512 thr / 8 waves, wave tile 32x32.
// LDS depth-2: Af[2][4096] f32 (32KB, src-swizzled u^=(row&7)),
// Bl[2][8192] f16 (32KB linear). 64KB -> 2 blocks/CU (grid 512).
// Per wave per iter: 4 gl_lds (2 A + 2 B); in-loop wait vmcnt(4).
__global__ __launch_bounds__(512) void gemm_part_k(const float* __restrict__ A,
                                                   const _Float16* __restrict__ Bf,
                                                   float* __restrict__ part) {
  __shared__ __align__(16) char smem[65536];    // 32KB A + 32KB B
  float*    Afs = (float*)smem;                 // [2][4096] f32
  _Float16* Bls = (_Float16*)(smem + 32768);    // [2][8192] f16

  const int t = threadIdx.x, lane = t & 63, w = t >> 6;
  const int fr = lane & 15, fg = lane >> 4;
  const int ks = blockIdx.y;
  const size_t row0 = (size_t)blockIdx.x * 64;
  const int k0 = ks * 2048;

  // staging: 32 instrs, id = w*4+q. id<16: A rows id*4+(lane>>4) (256B slice,
  // source-XOR-swizzled); else B linear 1KB chunks of global k-tile ks*32+T.
#define STAGE(T, P)                                                           \
  do {                                                                        \
    float* abase = Afs + (P)*4096;                                            \
    _Float16* bbase = Bls + (P)*8192;                                         \
    _Pragma("unroll") for (int q_ = 0; q_ < 4; ++q_) {                        \
      const int id_ = w * 4 + q_;                                             \
      if (id_ < 16) {                                                         \
        const int r_ = id_ * 4 + (lane >> 4);                                 \
        gl_lds16f(A + (size_t)(row0 + r_) * D_IN + k0 + (T)*64 +              \
                      (((lane & 15) ^ (r_ & 7)) << 2),                        \
                  abase + id_ * 256);                                         \
      } else {                                                                \
        const int ib_ = id_ - 16;                                             \
        gl_lds16h(Bf + ((size_t)(ks * 32 + (T))) * 8192 + ib_ * 512 + lane * 8, \
                  bbase + ib_ * 512);                                         \
      }                                                                       \
    }                                                                         \
  } while (0)

  // frag read offsets: wave tile rows wm*32..+32, cols wn*32..+32
  const int wm = w >> 2, wn = w & 3;
  int aoff[2][2][2], boff[2][2];
#pragma unroll
  for (int i = 0; i < 2; ++i)
#pragma unroll
    for (int c = 0; c < 2; ++c)
#pragma unroll
      for (int h = 0; h < 2; ++h)
        aoff[i][c][h] = (wm * 32 + i * 16 + fr) * 64 +
                        (((c * 8 + fg * 2 + h) ^ (fr & 7)) * 4);
#pragma unroll
  for (int c = 0; c < 2; ++c)
#pragma unroll
    for (int j = 0; j < 2; ++j)
      boff[c][j] = c * 4096 + (wn * 2 + j) * 512 + lane * 8;

  f32x4_t acc[2][2] = {};

  STAGE(0, 0);
  for (int kt = 0; kt < 32; ++kt) {
    if (kt < 31) STAGE(kt + 1, (kt + 1) & 1);
    __builtin_amdgcn_sched_barrier(0);
    if (kt < 31) asm volatile("s_waitcnt vmcnt(4)" ::: "memory");
    else         asm volatile("s_waitcnt vmcnt(0)" ::: "memory");
    __builtin_amdgcn_s_barrier();
    __builtin_amdgcn_sched_barrier(0);

    const float*    Ap = Afs + (kt & 1) * 4096;
    const _Float16* Bp = Bls + (kt & 1) * 8192;
#pragma unroll
    for (int c = 0; c < 2; ++c) {
      half8_t bfv[2];
#pragma unroll
      for (int j = 0; j < 2; ++j) bfv[j] = *(const half8_t*)(Bp + boff[c][j]);
#pragma unroll
      for (int i = 0; i < 2; ++i) {
        const float4 x0 = *(const float4*)(Ap + aoff[i][c][0]);
        const float4 x1 = *(const float4*)(Ap + aoff[i][c][1]);
        const half8_t af = cvt8(x0, x1);
#pragma unroll
        for (int j = 0; j < 2; ++j)
          acc[i][j] = __builtin_amdgcn_mfma_f32_16x16x32_f16(af, bfv[j], acc[i][j], 0, 0, 0);
      }
    }
    asm volatile("s_waitcnt lgkmcnt(0)" ::: "memory");
    __builtin_amdgcn_s_barrier();
    __builtin_amdgcn_sched_barrier(0);
  }
#undef STAGE

  // epilogue: C/D layout row=...fg*4+r, col=...j*16+fr  [m89]
  float* pb = part + ((size_t)ks * NUM_B + row0) * 128;
#pragma unroll
  for (int i = 0; i < 2; ++i)
#pragma unroll
    for (int j = 0; j < 2; ++j) {
      const int col = wn * 32 + j * 16 + fr;
#pragma unroll
      for (int r = 0; r < 4; ++r)
        pb[(size_t)(wm * 32 + i * 16 + fg * 4 + r) * 128 + col] = acc[i][j][r];
    }
}

// ---------------------------------------------------------------------------
// Coalesced split-K reduce + gather + bias + log_softmax. One wave per row.
// Lane l holds cols {2l,2l+1}; gather via shuffle from lane aidx>>1.
__global__ __launch_bounds__(256) void softmax_k(const float* __restrict__ part,
                                                 const float* __restrict__ bqk,
                                                 const int* __restrict__ va,
                                                 const int* __restrict__ phase,
                                                 const int* __restrict__ trick,
                                                 const float* __restrict__ psig,
                                                 float* __restrict__ out) {
  const int t = threadIdx.x;
  const int lane = t & 63, w = t >> 6;
  const int b = blockIdx.x * 4 + w;

  float sx = 0.f, sy = 0.f;
#pragma unroll
  for (int ks = 0; ks < 2; ++ks) {
    const float2 v = *(const float2*)&part[((size_t)ks * NUM_B + b) * 128 + lane * 2];
    sx += v.x; sy += v.y;
  }

  int rank = -1, suit = 0;
  if (lane < N_ACT) {
    rank = va[((size_t)b * N_ACT + lane) * 2];
    suit = va[((size_t)b * N_ACT + lane) * 2 + 1];
  }
  const int ph = phase[b];
  const bool valid = (rank >= 0);
  const int aidx = valid ? (suit == 4 ? 80 : ph * 40 + suit * 9 + rank) : -1;
  const int nvalid = __popcll(__ballot(valid));

  const int srcl = valid ? (aidx >> 1) : 0;
  const float v0 = __shfl(sx, srcl);
  const float v1 = __shfl(sy, srcl);

  float attn_l = -INFINITY;
  if (valid) attn_l = (((aidx & 1) ? v1 : v0) + bqk[aidx]) * 0.0625f;  // /sqrt(256)

  if (ph == 1 && lane == 0) {
    const float ps = psig[trick[b]];
    const float nv = (float)nvalid;
    const float wv = (nv == 1.0f) ? 0.0f
                                  : logf(fmaxf((1.0f - ps) / ps * (nv - 1.0f), 1e-5f));
    attn_l += wv;
  }

  float m = attn_l;
#pragma unroll
  for (int off = 1; off < 64; off <<= 1) m = fmaxf(m, __shfl_xor(m, off));
  const float e = expf(attn_l - m);
  float ssum = e;
#pragma unroll
  for (int off = 1; off < 64; off <<= 1) ssum += __shfl_xor(ssum, off);
  const float o = attn_l - m - logf(ssum);
  // finite sentinel at masked positions (ref has -inf; (-inf)-(-inf)=NaN fails)
  if (lane < N_ACT) out[(size_t)b * N_ACT + lane] = valid ? o : -3.0e38f;
}

// ---------------------------------------------------------------------------
extern "C" void kernel_launch(void* const* d_in, const int* in_sizes, int n_in,
                              void* d_out, int out_size, void* d_ws, size_t ws_size,
                              hipStream_t stream) {
  const float* backbone = (const float*)d_in[0];
  const int*   va       = (const int*)d_in[1];
  const int*   phase    = (const int*)d_in[2];
  const int*   trick    = (const int*)d_in[3];
  const float* Wq       = (const float*)d_in[4];
  const float* bq       = (const float*)d_in[5];
  const float* keytab   = (const float*)d_in[6];
  const float* gamma    = (const float*)d_in[7];
  const float* beta     = (const float*)d_in[8];
  const float* psig     = (const float*)d_in[9];
  float* out = (float*)d_out;

  char* ws = (char*)d_ws;
  _Float16* Bf   = (_Float16*)ws;                             // 1 MB
  float* tableLN = (float*)(ws + (1u << 20));                 // 83 KB
  float* bqk     = (float*)(ws + (1u << 20) + (128u << 10));  // 324 B
  float* part    = (float*)(ws + (2u << 20));                 // 16.8 MB

  ln_table_k<<<dim3(81), 256, 0, stream>>>(keytab, gamma, beta, bq, tableLN, bqk);
  wk_gemm_k<<<dim3(64), 256, 0, stream>>>(Wq, tableLN, Bf);
  gemm_part_k<<<dim3(NUM_B / 64, 2), 512, 0, stream>>>(backbone, Bf, part);
  softmax_k<<<dim3(NUM_B / 4), 256, 0, stream>>>(part, bqk, va, phase, trick,
                                                 psig, out);
}